// Round 10
// baseline (478.125 us; speedup 1.0000x reference)
//
#include <hip/hip_runtime.h>

#define D 64
#define K 1024
#define HWSZ 1024
#define QUANT_ELEMS 4194304            // 64*64*32*32
#define TAU_H 1e-3f                    // gap threshold, halved-score domain (== 2e-3 full)
#define NTOK 65536

typedef __attribute__((ext_vector_type(8))) short short8;
typedef __attribute__((ext_vector_type(4))) float floatx4;

union Frag { short8 v; unsigned u[4]; };

#define MFMA(a, b, c) __builtin_amdgcn_mfma_f32_16x16x32_bf16((a), (b), (c), 0, 0, 0)

// round f32 -> bf16 (rne), return as f32 bit pattern (low 16 zeroed)
static __device__ inline unsigned bf16_hi_bits(float f) {
    unsigned u = __builtin_bit_cast(unsigned, f);
    return (u + 0x7fffu + ((u >> 16) & 1u)) & 0xffff0000u;
}

// split (a,b) into bf16 hi pair and bf16 lo (residual) pair, each packed in one u32
static __device__ inline void split2(float a, float b, unsigned& hi, unsigned& lo) {
    unsigned ha = bf16_hi_bits(a);
    unsigned hb = bf16_hi_bits(b);
    hi = hb | (ha >> 16);
    float ra = a - __builtin_bit_cast(float, ha);
    float rb = b - __builtin_bit_cast(float, hb);
    lo = bf16_hi_bits(rb) | (bf16_hi_bits(ra) >> 16);
}

// ---------------- prep: codebook -> MFMA B-frag layout (hi/lo) + 0.5||e||^2 ----------------
// G[(tile*4+frag)*64+lane], frag in {h_kh0, h_kh1, l_kh0, l_kh1}
// B lane mapping: code = lane&15, k = (lane>>4)*8 + j, d = kh*32 + k
__global__ void vq_prep(const float* __restrict__ emb, double* __restrict__ acc,
                        float* __restrict__ enorm_h, short8* __restrict__ G) {
    const int tid = threadIdx.x;
    const int lane = tid & 63;
    const int w = tid >> 6;
    const int lhi = lane >> 4, llo = lane & 15;
    const int tile = blockIdx.x * 4 + w;
    if (blockIdx.x == 0 && tid == 0) *acc = 0.0;

    const int code = tile * 16 + llo;
    const float* ep = emb + (size_t)code * D + lhi * 8;
    floatx4 e0 = *(const floatx4*)(ep);
    floatx4 e1 = *(const floatx4*)(ep + 4);
    floatx4 e2 = *(const floatx4*)(ep + 32);
    floatx4 e3 = *(const floatx4*)(ep + 36);
    Frag h0, l0, h1, l1;
    split2(e0.x, e0.y, h0.u[0], l0.u[0]); split2(e0.z, e0.w, h0.u[1], l0.u[1]);
    split2(e1.x, e1.y, h0.u[2], l0.u[2]); split2(e1.z, e1.w, h0.u[3], l0.u[3]);
    split2(e2.x, e2.y, h1.u[0], l1.u[0]); split2(e2.z, e2.w, h1.u[1], l1.u[1]);
    split2(e3.x, e3.y, h1.u[2], l1.u[2]); split2(e3.z, e3.w, h1.u[3], l1.u[3]);
    G[((size_t)tile * 4 + 0) * 64 + lane] = h0.v;
    G[((size_t)tile * 4 + 1) * 64 + lane] = h1.v;
    G[((size_t)tile * 4 + 2) * 64 + lane] = l0.v;
    G[((size_t)tile * 4 + 3) * 64 + lane] = l1.v;

    float s = e0.x * e0.x + e0.y * e0.y + e0.z * e0.z + e0.w * e0.w
            + e1.x * e1.x + e1.y * e1.y + e1.z * e1.z + e1.w * e1.w
            + e2.x * e2.x + e2.y * e2.y + e2.z * e2.z + e2.w * e2.w
            + e3.x * e3.x + e3.y * e3.y + e3.z * e3.z + e3.w * e3.w;
    s += __shfl_xor(s, 16);
    s += __shfl_xor(s, 32);
    if (lhi == 0) enorm_h[code] = 0.5f * s;
}

// ---------------- pass 1: quarter codebook per block, 32KB LDS in 2 phases ----------------
// grid: 1024 blocks = quarter q (bid>>8) x token-group t (bid&255); 512 thr
// 34 KB LDS + 52 VGPR -> 4 blocks/CU = 8 waves/SIMD (max TLP)
__global__ __launch_bounds__(512, 8) void vq_scan(const float* __restrict__ x,
                                                  const float* __restrict__ enorm_h,
                                                  const short8* __restrict__ G,
                                                  float2* __restrict__ pm_g,
                                                  int* __restrict__ pidx_g,
                                                  float* __restrict__ xnorm_g) {
    const int tid = threadIdx.x;
    const int lane = tid & 63;
    const int w = __builtin_amdgcn_readfirstlane(tid >> 6);  // wave 0..7
    const int lhi = lane >> 4, llo = lane & 15;
    const int q = blockIdx.x >> 8;          // codebook quarter 0..3
    const int t = blockIdx.x & 255;         // token group

    __shared__ short8 fbq[2048];            // 8 tiles x 4 frags x 64 lanes = 32 KB (one phase)
    __shared__ float en_q[256];             // 1 KB

    const int tb = t * 256;
    const int bb = tb >> 10;
    const int hwb = tb & 1023;
    const float* xbase = x + (size_t)bb * (D * HWSZ);
    const short8* Gq = G + (size_t)q * 4096;

    // ---- stage phase 0 (tiles 0..7 of the quarter) ----
#pragma unroll
    for (int j = 0; j < 4; ++j)
        __builtin_amdgcn_global_load_lds(
            (const __attribute__((address_space(1))) void*)(Gq + (size_t)j * 512 + tid),
            (__attribute__((address_space(3))) void*)&fbq[j * 512 + tid],
            16, 0, 0);
    if (tid < 256) en_q[tid] = enorm_h[q * 256 + tid];

    // ---- load & convert this wave's 32 tokens (2 sets of 16), A NEGATED ----
    // A mapping: row(token) = llo, k = lhi*8 + j, d = kh*32 + k
    short8 Ah[2][2], Al[2][2];
#pragma unroll
    for (int s = 0; s < 2; ++s) {
        const int hw = hwb + w * 32 + s * 16 + llo;
        float xn = 0.f;
        Frag ah[2], al[2];
#pragma unroll
        for (int kh = 0; kh < 2; ++kh) {
            const float* xp = xbase + (size_t)(kh * 32 + lhi * 8) * HWSZ + hw;
            float v[8];
#pragma unroll
            for (int j = 0; j < 8; ++j) { v[j] = -xp[(size_t)j * HWSZ]; xn += v[j] * v[j]; }
#pragma unroll
            for (int p = 0; p < 4; ++p)
                split2(v[2 * p], v[2 * p + 1], ah[kh].u[p], al[kh].u[p]);
        }
        xn += __shfl_xor(xn, 16);
        xn += __shfl_xor(xn, 32);
        if (q == 0 && lhi == 0) xnorm_g[tb + w * 32 + s * 16 + llo] = xn;
        Ah[s][0] = ah[0].v; Ah[s][1] = ah[1].v;
        Al[s][0] = al[0].v; Al[s][1] = al[1].v;
    }

    float m1[2][4], m2[2][4];
#pragma unroll
    for (int s = 0; s < 2; ++s)
#pragma unroll
        for (int i = 0; i < 4; ++i) { m1[s][i] = 1e30f; m2[s][i] = 1e30f; }

    __syncthreads();   // phase-0 staging complete (implicit vmcnt drain)

    // ---- hot loop: 2 phases x 8 tiles; acc seeded with 0.5||e||^2, A negated ----
    for (int h = 0; h < 2; ++h) {
        if (h) {
            __syncthreads();   // all reads of phase 0 done
#pragma unroll
            for (int j = 0; j < 4; ++j)
                __builtin_amdgcn_global_load_lds(
                    (const __attribute__((address_space(1))) void*)(Gq + 2048 + (size_t)j * 512 + tid),
                    (__attribute__((address_space(3))) void*)&fbq[j * 512 + tid],
                    16, 0, 0);
            __syncthreads();   // phase-1 staging complete
        }
#pragma unroll
        for (int tt = 0; tt < 8; ++tt) {
            const int tile = h * 8 + tt;
            short8 B0 = fbq[(tt * 4 + 0) * 64 + lane];   // e_hi kh0
            short8 B1 = fbq[(tt * 4 + 1) * 64 + lane];   // e_hi kh1
            short8 B2 = fbq[(tt * 4 + 2) * 64 + lane];   // e_lo kh0
            short8 B3 = fbq[(tt * 4 + 3) * 64 + lane];   // e_lo kh1
            const float en_ = en_q[tile * 16 + llo];
#pragma unroll
            for (int s = 0; s < 2; ++s) {
                floatx4 accA = {en_, en_, en_, en_};
                floatx4 accB = {0.f, 0.f, 0.f, 0.f};
                __builtin_amdgcn_s_setprio(1);
                accA = MFMA(Ah[s][0], B0, accA);
                accB = MFMA(Ah[s][1], B1, accB);
                accA = MFMA(Al[s][0], B0, accA);
                accB = MFMA(Al[s][1], B1, accB);
                accA = MFMA(Ah[s][0], B2, accA);
                accB = MFMA(Ah[s][1], B3, accB);
                __builtin_amdgcn_s_setprio(0);
#pragma unroll
                for (int i = 0; i < 4; ++i) {
                    float sc = accA[i] + accB[i];            // 0.5||e||^2 - x.e
                    unsigned pb = (__builtin_bit_cast(unsigned, sc) & 0xFFFFFFF0u) | (unsigned)tile;
                    float scp = __builtin_bit_cast(float, pb);
                    m2[s][i] = __builtin_amdgcn_fmed3f(scp, m1[s][i], m2[s][i]);
                    m1[s][i] = fminf(m1[s][i], scp);
                }
            }
        }
    }

    // ---- cross-lane argmin reduce over the 16 code-lanes; write per-quarter partials ----
#pragma unroll
    for (int s = 0; s < 2; ++s)
#pragma unroll
        for (int i = 0; i < 4; ++i) {
            float a1 = m1[s][i], a2 = m2[s][i];
            int ai = (int)(((__builtin_bit_cast(unsigned, a1) & 15u) << 4) | (unsigned)llo);
#pragma unroll
            for (int sft = 1; sft < 16; sft <<= 1) {
                float o1 = __shfl_xor(a1, sft);
                float o2 = __shfl_xor(a2, sft);
                int oi = __shfl_xor(ai, sft);
                float big = fmaxf(a1, o1);
                a2 = fminf(fminf(a2, o2), big);
                if (o1 < a1 || (o1 == a1 && oi < ai)) { a1 = o1; ai = oi; }
                ai = (int)(((__builtin_bit_cast(unsigned, a1) & 15u) << 4) | ((unsigned)ai & 15u));
            }
            if (llo == 0) {
                const int tok = tb + w * 32 + s * 16 + lhi * 4 + i;
                float m1c = __builtin_bit_cast(float, __builtin_bit_cast(unsigned, a1) & 0xFFFFFFF0u);
                float m2c = __builtin_bit_cast(float, __builtin_bit_cast(unsigned, a2) & 0xFFFFFFF0u);
                pm_g[(size_t)q * NTOK + tok] = make_float2(m1c, m2c);
                pidx_g[(size_t)q * NTOK + tok] = q * 256 + ai;
            }
        }
}

// ---------------- pass 2: merge quarters, tie rescore, loss, epilogue ----------------
__global__ __launch_bounds__(256, 4) void vq_merge(const float* __restrict__ x,
                                                   const float* __restrict__ emb,
                                                   const float2* __restrict__ pm_g,
                                                   const int* __restrict__ pidx_g,
                                                   const float* __restrict__ xnorm_g,
                                                   float* __restrict__ out,
                                                   double* __restrict__ loss_acc) {
    const int tid = threadIdx.x;
    const int lane = tid & 63;
    const int w = tid >> 6;

    __shared__ int sfinal[256];
    __shared__ double sloss[256];
    __shared__ int s_flaglist[256];
    __shared__ int s_nflag;
    __shared__ double rbv[4];
    __shared__ int rbi[4];
    __shared__ double lred[4];

    if (tid == 0) s_nflag = 0;
    __syncthreads();

    const int tb = blockIdx.x * 256;
    const int tok = tb + tid;
    const int bb = tb >> 10;
    const int hwb = tb & 1023;

    // ---- merge 4 quarter-partials ----
    float2 p0 = pm_g[tok];
    float a1 = p0.x, a2 = p0.y;
    int ai = pidx_g[tok];
#pragma unroll
    for (int qq = 1; qq < 4; ++qq) {
        float2 pq = pm_g[(size_t)qq * NTOK + tok];
        int bi = pidx_g[(size_t)qq * NTOK + tok];
        float nm2 = fminf(fmaxf(a1, pq.x), fminf(a2, pq.y));
        if (pq.x < a1 || (pq.x == a1 && bi < ai)) { a1 = pq.x; ai = bi; }
        a2 = nm2;
    }
    sfinal[tid] = ai;
    sloss[tid] = (double)(xnorm_g[tok] + 2.0f * a1);   // ||x||^2 + 2*s_min
    if (a2 - a1 < TAU_H) {
        int p = atomicAdd(&s_nflag, 1);
        s_flaglist[p] = tid;
    }
    __syncthreads();

    // ---- rare: fp64 full rescore for near-tie tokens (block-cooperative) ----
    const int nf = s_nflag;
    for (int f = 0; f < nf; ++f) {
        const int tloc = s_flaglist[f];
        const int tg = tb + tloc;
        const float* xf = x + (size_t)(tg >> 10) * (D * HWSZ) + (tg & 1023);
        double bv = 1e300;
        int bi = 0x7fffffff;
        for (int kk = tid; kk < K; kk += 256) {
            const float* ek = emb + (size_t)kk * D;
            double a = 0.0;
#pragma unroll 8
            for (int d = 0; d < D; ++d) {
                double diff = (double)xf[(size_t)d * HWSZ] - (double)ek[d];
                a += diff * diff;
            }
            if (a < bv || (a == bv && kk < bi)) { bv = a; bi = kk; }
        }
        for (int off = 32; off; off >>= 1) {
            double ov = __shfl_down(bv, off);
            int oi = __shfl_down(bi, off);
            if (ov < bv || (ov == bv && oi < bi)) { bv = ov; bi = oi; }
        }
        if (lane == 0) { rbv[w] = bv; rbi[w] = bi; }
        __syncthreads();
        if (tid == 0) {
            double fv = rbv[0];
            int fi = rbi[0];
#pragma unroll
            for (int c = 1; c < 4; ++c)
                if (rbv[c] < fv || (rbv[c] == fv && rbi[c] < fi)) { fv = rbv[c]; fi = rbi[c]; }
            sfinal[tloc] = fi;
            sloss[tloc] = fv;
        }
        __syncthreads();
    }

    // ---- loss reduce + atomic ----
    double lacc = sloss[tid];
    for (int off = 32; off; off >>= 1) lacc += __shfl_xor(lacc, off);
    if (lane == 0) lred[w] = lacc;
    __syncthreads();
    if (tid == 0) atomicAdd(loss_acc, lred[0] + lred[1] + lred[2] + lred[3]);

    // ---- epilogue: out[bb][d][hwb+tid] = emb[idx][d] (coalesced across tid per d) ----
    const int qidx = sfinal[tid];
    const floatx4* eq = (const floatx4*)(emb + (size_t)qidx * D);
    float* op = out + (size_t)bb * (D * HWSZ) + hwb + tid;
#pragma unroll
    for (int j = 0; j < 16; ++j) {
        floatx4 e4 = eq[j];
        op[(size_t)(j * 4 + 0) * HWSZ] = e4.x;
        op[(size_t)(j * 4 + 1) * HWSZ] = e4.y;
        op[(size_t)(j * 4 + 2) * HWSZ] = e4.z;
        op[(size_t)(j * 4 + 3) * HWSZ] = e4.w;
    }
}

__global__ void vq_finalize(const double* __restrict__ acc, float* __restrict__ out) {
    out[QUANT_ELEMS] = (float)(1.25 * (*acc) / (double)QUANT_ELEMS);
}

extern "C" void kernel_launch(void* const* d_in, const int* in_sizes, int n_in,
                              void* d_out, int out_size, void* d_ws, size_t ws_size,
                              hipStream_t stream) {
    const float* x = (const float*)d_in[0];
    const float* emb = (const float*)d_in[1];
    float* out = (float*)d_out;
    char* ws = (char*)d_ws;

    double* acc     = (double*)(ws);                 // 8 B
    float* enorm_h  = (float*)(ws + 4096);           // 4 KB
    short8* G       = (short8*)(ws + 16384);         // 256 KB -> ends at 278528
    float2* pm_g    = (float2*)(ws + 278528);        // 2 MB   -> ends at 2375680
    int* pidx_g     = (int*)(ws + 2375680);          // 1 MB   -> ends at 3424256
    float* xnorm_g  = (float*)(ws + 3424256);        // 256 KB -> ends at 3686400

    vq_prep<<<16, 256, 0, stream>>>(emb, acc, enorm_h, G);
    vq_scan<<<1024, 512, 0, stream>>>(x, enorm_h, G, pm_g, pidx_g, xnorm_g);
    vq_merge<<<256, 256, 0, stream>>>(x, emb, pm_g, pidx_g, xnorm_g, out, acc);
    vq_finalize<<<1, 1, 0, stream>>>(acc, out);
}

// Round 11
// 279.002 us; speedup vs baseline: 1.7137x; 1.7137x over previous
//
#include <hip/hip_runtime.h>

#define D 64
#define K 1024
#define HWSZ 1024
#define QUANT_ELEMS 4194304            // 64*64*32*32
#define TAU_H 1e-3f                    // gap threshold, halved-score domain (== 2e-3 full)
#define NTOK 65536

typedef __attribute__((ext_vector_type(8))) short short8;
typedef __attribute__((ext_vector_type(4))) float floatx4;

union Frag { short8 v; unsigned u[4]; };

#define MFMA(a, b, c) __builtin_amdgcn_mfma_f32_16x16x32_bf16((a), (b), (c), 0, 0, 0)

// round f32 -> bf16 (rne), return as f32 bit pattern (low 16 zeroed)
static __device__ inline unsigned bf16_hi_bits(float f) {
    unsigned u = __builtin_bit_cast(unsigned, f);
    return (u + 0x7fffu + ((u >> 16) & 1u)) & 0xffff0000u;
}

// split (a,b) into bf16 hi pair and bf16 lo (residual) pair, each packed in one u32
static __device__ inline void split2(float a, float b, unsigned& hi, unsigned& lo) {
    unsigned ha = bf16_hi_bits(a);
    unsigned hb = bf16_hi_bits(b);
    hi = hb | (ha >> 16);
    float ra = a - __builtin_bit_cast(float, ha);
    float rb = b - __builtin_bit_cast(float, hb);
    lo = bf16_hi_bits(rb) | (bf16_hi_bits(ra) >> 16);
}

// ---------------- prep: codebook -> MFMA B-frag layout (hi/lo) + 0.5||e||^2 ----------------
// G[(tile*4+frag)*64+lane], frag in {h_kh0, h_kh1, l_kh0, l_kh1}
// B lane mapping: code = lane&15, k = (lane>>4)*8 + j, d = kh*32 + k
__global__ void vq_prep(const float* __restrict__ emb, double* __restrict__ acc,
                        float* __restrict__ enorm_h, short8* __restrict__ G) {
    const int tid = threadIdx.x;
    const int lane = tid & 63;
    const int w = tid >> 6;
    const int lhi = lane >> 4, llo = lane & 15;
    const int tile = blockIdx.x * 4 + w;
    if (blockIdx.x == 0 && tid == 0) *acc = 0.0;

    const int code = tile * 16 + llo;
    const float* ep = emb + (size_t)code * D + lhi * 8;
    floatx4 e0 = *(const floatx4*)(ep);
    floatx4 e1 = *(const floatx4*)(ep + 4);
    floatx4 e2 = *(const floatx4*)(ep + 32);
    floatx4 e3 = *(const floatx4*)(ep + 36);
    Frag h0, l0, h1, l1;
    split2(e0.x, e0.y, h0.u[0], l0.u[0]); split2(e0.z, e0.w, h0.u[1], l0.u[1]);
    split2(e1.x, e1.y, h0.u[2], l0.u[2]); split2(e1.z, e1.w, h0.u[3], l0.u[3]);
    split2(e2.x, e2.y, h1.u[0], l1.u[0]); split2(e2.z, e2.w, h1.u[1], l1.u[1]);
    split2(e3.x, e3.y, h1.u[2], l1.u[2]); split2(e3.z, e3.w, h1.u[3], l1.u[3]);
    G[((size_t)tile * 4 + 0) * 64 + lane] = h0.v;
    G[((size_t)tile * 4 + 1) * 64 + lane] = h1.v;
    G[((size_t)tile * 4 + 2) * 64 + lane] = l0.v;
    G[((size_t)tile * 4 + 3) * 64 + lane] = l1.v;

    float s = e0.x * e0.x + e0.y * e0.y + e0.z * e0.z + e0.w * e0.w
            + e1.x * e1.x + e1.y * e1.y + e1.z * e1.z + e1.w * e1.w
            + e2.x * e2.x + e2.y * e2.y + e2.z * e2.z + e2.w * e2.w
            + e3.x * e3.x + e3.y * e3.y + e3.z * e3.z + e3.w * e3.w;
    s += __shfl_xor(s, 16);
    s += __shfl_xor(s, 32);
    if (lhi == 0) enorm_h[code] = 0.5f * s;
}

// ---------------- pass 1: quarter codebook per block, 32KB LDS in 2 phases ----------------
// grid: 1024 blocks = quarter q (bid>>8) x token-group t (bid&255); 512 thr
// 34 KB LDS + ~52 VGPR (NO aggressive launch_bounds: R10's (512,8) forced VGPR=32 -> spill,
// FETCH 1 GB, 478us) -> 4 blocks/CU by LDS, 8 waves/SIMD by actual VGPR <= 64
__global__ __launch_bounds__(512, 4) void vq_scan(const float* __restrict__ x,
                                                  const float* __restrict__ enorm_h,
                                                  const short8* __restrict__ G,
                                                  float2* __restrict__ pm_g,
                                                  int* __restrict__ pidx_g,
                                                  float* __restrict__ xnorm_g) {
    const int tid = threadIdx.x;
    const int lane = tid & 63;
    const int w = __builtin_amdgcn_readfirstlane(tid >> 6);  // wave 0..7
    const int lhi = lane >> 4, llo = lane & 15;
    const int q = blockIdx.x >> 8;          // codebook quarter 0..3
    const int t = blockIdx.x & 255;         // token group

    __shared__ short8 fbq[2048];            // 8 tiles x 4 frags x 64 lanes = 32 KB (one phase)
    __shared__ float en_q[256];             // 1 KB

    const int tb = t * 256;
    const int bb = tb >> 10;
    const int hwb = tb & 1023;
    const float* xbase = x + (size_t)bb * (D * HWSZ);
    const short8* Gq = G + (size_t)q * 4096;

    // ---- stage phase 0 (tiles 0..7 of the quarter) ----
#pragma unroll
    for (int j = 0; j < 4; ++j)
        __builtin_amdgcn_global_load_lds(
            (const __attribute__((address_space(1))) void*)(Gq + (size_t)j * 512 + tid),
            (__attribute__((address_space(3))) void*)&fbq[j * 512 + tid],
            16, 0, 0);
    if (tid < 256) en_q[tid] = enorm_h[q * 256 + tid];

    // ---- load & convert this wave's 32 tokens (2 sets of 16), A NEGATED ----
    // A mapping: row(token) = llo, k = lhi*8 + j, d = kh*32 + k
    short8 Ah[2][2], Al[2][2];
#pragma unroll
    for (int s = 0; s < 2; ++s) {
        const int hw = hwb + w * 32 + s * 16 + llo;
        float xn = 0.f;
        Frag ah[2], al[2];
#pragma unroll
        for (int kh = 0; kh < 2; ++kh) {
            const float* xp = xbase + (size_t)(kh * 32 + lhi * 8) * HWSZ + hw;
            float v[8];
#pragma unroll
            for (int j = 0; j < 8; ++j) { v[j] = -xp[(size_t)j * HWSZ]; xn += v[j] * v[j]; }
#pragma unroll
            for (int p = 0; p < 4; ++p)
                split2(v[2 * p], v[2 * p + 1], ah[kh].u[p], al[kh].u[p]);
        }
        xn += __shfl_xor(xn, 16);
        xn += __shfl_xor(xn, 32);
        if (q == 0 && lhi == 0) xnorm_g[tb + w * 32 + s * 16 + llo] = xn;
        Ah[s][0] = ah[0].v; Ah[s][1] = ah[1].v;
        Al[s][0] = al[0].v; Al[s][1] = al[1].v;
    }

    float m1[2][4], m2[2][4];
#pragma unroll
    for (int s = 0; s < 2; ++s)
#pragma unroll
        for (int i = 0; i < 4; ++i) { m1[s][i] = 1e30f; m2[s][i] = 1e30f; }

    __syncthreads();   // phase-0 staging complete (implicit vmcnt drain)

    // ---- hot loop: 2 phases x 8 tiles; acc seeded with 0.5||e||^2, A negated ----
    for (int h = 0; h < 2; ++h) {
        if (h) {
            __syncthreads();   // all reads of phase 0 done
#pragma unroll
            for (int j = 0; j < 4; ++j)
                __builtin_amdgcn_global_load_lds(
                    (const __attribute__((address_space(1))) void*)(Gq + 2048 + (size_t)j * 512 + tid),
                    (__attribute__((address_space(3))) void*)&fbq[j * 512 + tid],
                    16, 0, 0);
            __syncthreads();   // phase-1 staging complete
        }
#pragma unroll
        for (int tt = 0; tt < 8; ++tt) {
            const int tile = h * 8 + tt;
            short8 B0 = fbq[(tt * 4 + 0) * 64 + lane];   // e_hi kh0
            short8 B1 = fbq[(tt * 4 + 1) * 64 + lane];   // e_hi kh1
            short8 B2 = fbq[(tt * 4 + 2) * 64 + lane];   // e_lo kh0
            short8 B3 = fbq[(tt * 4 + 3) * 64 + lane];   // e_lo kh1
            const float en_ = en_q[tile * 16 + llo];
#pragma unroll
            for (int s = 0; s < 2; ++s) {
                floatx4 accA = {en_, en_, en_, en_};
                floatx4 accB = {0.f, 0.f, 0.f, 0.f};
                __builtin_amdgcn_s_setprio(1);
                accA = MFMA(Ah[s][0], B0, accA);
                accB = MFMA(Ah[s][1], B1, accB);
                accA = MFMA(Al[s][0], B0, accA);
                accB = MFMA(Al[s][1], B1, accB);
                accA = MFMA(Ah[s][0], B2, accA);
                accB = MFMA(Ah[s][1], B3, accB);
                __builtin_amdgcn_s_setprio(0);
#pragma unroll
                for (int i = 0; i < 4; ++i) {
                    float sc = accA[i] + accB[i];            // 0.5||e||^2 - x.e
                    unsigned pb = (__builtin_bit_cast(unsigned, sc) & 0xFFFFFFF0u) | (unsigned)tile;
                    float scp = __builtin_bit_cast(float, pb);
                    m2[s][i] = __builtin_amdgcn_fmed3f(scp, m1[s][i], m2[s][i]);
                    m1[s][i] = fminf(m1[s][i], scp);
                }
            }
        }
    }

    // ---- cross-lane argmin reduce over the 16 code-lanes; write per-quarter partials ----
#pragma unroll
    for (int s = 0; s < 2; ++s)
#pragma unroll
        for (int i = 0; i < 4; ++i) {
            float a1 = m1[s][i], a2 = m2[s][i];
            int ai = (int)(((__builtin_bit_cast(unsigned, a1) & 15u) << 4) | (unsigned)llo);
#pragma unroll
            for (int sft = 1; sft < 16; sft <<= 1) {
                float o1 = __shfl_xor(a1, sft);
                float o2 = __shfl_xor(a2, sft);
                int oi = __shfl_xor(ai, sft);
                float big = fmaxf(a1, o1);
                a2 = fminf(fminf(a2, o2), big);
                if (o1 < a1 || (o1 == a1 && oi < ai)) { a1 = o1; ai = oi; }
                ai = (int)(((__builtin_bit_cast(unsigned, a1) & 15u) << 4) | ((unsigned)ai & 15u));
            }
            if (llo == 0) {
                const int tok = tb + w * 32 + s * 16 + lhi * 4 + i;
                float m1c = __builtin_bit_cast(float, __builtin_bit_cast(unsigned, a1) & 0xFFFFFFF0u);
                float m2c = __builtin_bit_cast(float, __builtin_bit_cast(unsigned, a2) & 0xFFFFFFF0u);
                pm_g[(size_t)q * NTOK + tok] = make_float2(m1c, m2c);
                pidx_g[(size_t)q * NTOK + tok] = q * 256 + ai;
            }
        }
}

// ---------------- pass 2: merge quarters, tie rescore, loss, epilogue ----------------
__global__ __launch_bounds__(256, 4) void vq_merge(const float* __restrict__ x,
                                                   const float* __restrict__ emb,
                                                   const float2* __restrict__ pm_g,
                                                   const int* __restrict__ pidx_g,
                                                   const float* __restrict__ xnorm_g,
                                                   float* __restrict__ out,
                                                   double* __restrict__ loss_acc) {
    const int tid = threadIdx.x;
    const int lane = tid & 63;
    const int w = tid >> 6;

    __shared__ int sfinal[256];
    __shared__ double sloss[256];
    __shared__ int s_flaglist[256];
    __shared__ int s_nflag;
    __shared__ double rbv[4];
    __shared__ int rbi[4];
    __shared__ double lred[4];

    if (tid == 0) s_nflag = 0;
    __syncthreads();

    const int tb = blockIdx.x * 256;
    const int tok = tb + tid;
    const int bb = tb >> 10;
    const int hwb = tb & 1023;

    // ---- merge 4 quarter-partials ----
    float2 p0 = pm_g[tok];
    float a1 = p0.x, a2 = p0.y;
    int ai = pidx_g[tok];
#pragma unroll
    for (int qq = 1; qq < 4; ++qq) {
        float2 pq = pm_g[(size_t)qq * NTOK + tok];
        int bi = pidx_g[(size_t)qq * NTOK + tok];
        float nm2 = fminf(fmaxf(a1, pq.x), fminf(a2, pq.y));
        if (pq.x < a1 || (pq.x == a1 && bi < ai)) { a1 = pq.x; ai = bi; }
        a2 = nm2;
    }
    sfinal[tid] = ai;
    sloss[tid] = (double)(xnorm_g[tok] + 2.0f * a1);   // ||x||^2 + 2*s_min
    if (a2 - a1 < TAU_H) {
        int p = atomicAdd(&s_nflag, 1);
        s_flaglist[p] = tid;
    }
    __syncthreads();

    // ---- rare: fp64 full rescore for near-tie tokens (block-cooperative) ----
    const int nf = s_nflag;
    for (int f = 0; f < nf; ++f) {
        const int tloc = s_flaglist[f];
        const int tg = tb + tloc;
        const float* xf = x + (size_t)(tg >> 10) * (D * HWSZ) + (tg & 1023);
        double bv = 1e300;
        int bi = 0x7fffffff;
        for (int kk = tid; kk < K; kk += 256) {
            const float* ek = emb + (size_t)kk * D;
            double a = 0.0;
#pragma unroll 8
            for (int d = 0; d < D; ++d) {
                double diff = (double)xf[(size_t)d * HWSZ] - (double)ek[d];
                a += diff * diff;
            }
            if (a < bv || (a == bv && kk < bi)) { bv = a; bi = kk; }
        }
        for (int off = 32; off; off >>= 1) {
            double ov = __shfl_down(bv, off);
            int oi = __shfl_down(bi, off);
            if (ov < bv || (ov == bv && oi < bi)) { bv = ov; bi = oi; }
        }
        if (lane == 0) { rbv[w] = bv; rbi[w] = bi; }
        __syncthreads();
        if (tid == 0) {
            double fv = rbv[0];
            int fi = rbi[0];
#pragma unroll
            for (int c = 1; c < 4; ++c)
                if (rbv[c] < fv || (rbv[c] == fv && rbi[c] < fi)) { fv = rbv[c]; fi = rbi[c]; }
            sfinal[tloc] = fi;
            sloss[tloc] = fv;
        }
        __syncthreads();
    }

    // ---- loss reduce + atomic ----
    double lacc = sloss[tid];
    for (int off = 32; off; off >>= 1) lacc += __shfl_xor(lacc, off);
    if (lane == 0) lred[w] = lacc;
    __syncthreads();
    if (tid == 0) atomicAdd(loss_acc, lred[0] + lred[1] + lred[2] + lred[3]);

    // ---- epilogue: out[bb][d][hwb+tid] = emb[idx][d] (coalesced across tid per d) ----
    const int qidx = sfinal[tid];
    const floatx4* eq = (const floatx4*)(emb + (size_t)qidx * D);
    float* op = out + (size_t)bb * (D * HWSZ) + hwb + tid;
#pragma unroll
    for (int j = 0; j < 16; ++j) {
        floatx4 e4 = eq[j];
        op[(size_t)(j * 4 + 0) * HWSZ] = e4.x;
        op[(size_t)(j * 4 + 1) * HWSZ] = e4.y;
        op[(size_t)(j * 4 + 2) * HWSZ] = e4.z;
        op[(size_t)(j * 4 + 3) * HWSZ] = e4.w;
    }
}

__global__ void vq_finalize(const double* __restrict__ acc, float* __restrict__ out) {
    out[QUANT_ELEMS] = (float)(1.25 * (*acc) / (double)QUANT_ELEMS);
}

extern "C" void kernel_launch(void* const* d_in, const int* in_sizes, int n_in,
                              void* d_out, int out_size, void* d_ws, size_t ws_size,
                              hipStream_t stream) {
    const float* x = (const float*)d_in[0];
    const float* emb = (const float*)d_in[1];
    float* out = (float*)d_out;
    char* ws = (char*)d_ws;

    double* acc     = (double*)(ws);                 // 8 B
    float* enorm_h  = (float*)(ws + 4096);           // 4 KB
    short8* G       = (short8*)(ws + 16384);         // 256 KB -> ends at 278528
    float2* pm_g    = (float2*)(ws + 278528);        // 2 MB   -> ends at 2375680
    int* pidx_g     = (int*)(ws + 2375680);          // 1 MB   -> ends at 3424256
    float* xnorm_g  = (float*)(ws + 3424256);        // 256 KB -> ends at 3686400

    vq_prep<<<16, 256, 0, stream>>>(emb, acc, enorm_h, G);
    vq_scan<<<1024, 512, 0, stream>>>(x, enorm_h, G, pm_g, pidx_g, xnorm_g);
    vq_merge<<<256, 256, 0, stream>>>(x, emb, pm_g, pidx_g, xnorm_g, out, acc);
    vq_finalize<<<1, 1, 0, stream>>>(acc, out);
}

// Round 12
// 68.223 us; speedup vs baseline: 7.0082x; 4.0895x over previous
//
#include <hip/hip_runtime.h>

#define D 64
#define K 1024
#define HWSZ 1024
#define QUANT_ELEMS 4194304            // 64*64*32*32
#define TAU_H 1e-3f                    // gap threshold, halved-score domain (== 2e-3 full)
#define NTOK 65536

typedef __attribute__((ext_vector_type(8))) short short8;
typedef __attribute__((ext_vector_type(4))) float floatx4;

union Frag { short8 v; unsigned u[4]; };

#define MFMA(a, b, c) __builtin_amdgcn_mfma_f32_16x16x32_bf16((a), (b), (c), 0, 0, 0)

// round f32 -> bf16 (rne), return as f32 bit pattern (low 16 zeroed)
static __device__ inline unsigned bf16_hi_bits(float f) {
    unsigned u = __builtin_bit_cast(unsigned, f);
    return (u + 0x7fffu + ((u >> 16) & 1u)) & 0xffff0000u;
}

// split (a,b) into bf16 hi pair and bf16 lo (residual) pair, each packed in one u32
static __device__ inline void split2(float a, float b, unsigned& hi, unsigned& lo) {
    unsigned ha = bf16_hi_bits(a);
    unsigned hb = bf16_hi_bits(b);
    hi = hb | (ha >> 16);
    float ra = a - __builtin_bit_cast(float, ha);
    float rb = b - __builtin_bit_cast(float, hb);
    lo = bf16_hi_bits(rb) | (bf16_hi_bits(ra) >> 16);
}

// ---------------- prep: codebook -> MFMA B-frag layout (hi/lo) + 0.5||e||^2 ----------------
// G[(tile*4+frag)*64+lane], frag in {h_kh0, h_kh1, l_kh0, l_kh1}
// B lane mapping: code = lane&15, k = (lane>>4)*8 + j, d = kh*32 + k
__global__ void vq_prep(const float* __restrict__ emb, double* __restrict__ acc,
                        float* __restrict__ enorm_h, short8* __restrict__ G) {
    const int tid = threadIdx.x;
    const int lane = tid & 63;
    const int w = tid >> 6;
    const int lhi = lane >> 4, llo = lane & 15;
    const int tile = blockIdx.x * 4 + w;
    if (blockIdx.x == 0 && tid == 0) *acc = 0.0;

    const int code = tile * 16 + llo;
    const float* ep = emb + (size_t)code * D + lhi * 8;
    floatx4 e0 = *(const floatx4*)(ep);
    floatx4 e1 = *(const floatx4*)(ep + 4);
    floatx4 e2 = *(const floatx4*)(ep + 32);
    floatx4 e3 = *(const floatx4*)(ep + 36);
    Frag h0, l0, h1, l1;
    split2(e0.x, e0.y, h0.u[0], l0.u[0]); split2(e0.z, e0.w, h0.u[1], l0.u[1]);
    split2(e1.x, e1.y, h0.u[2], l0.u[2]); split2(e1.z, e1.w, h0.u[3], l0.u[3]);
    split2(e2.x, e2.y, h1.u[0], l1.u[0]); split2(e2.z, e2.w, h1.u[1], l1.u[1]);
    split2(e3.x, e3.y, h1.u[2], l1.u[2]); split2(e3.z, e3.w, h1.u[3], l1.u[3]);
    G[((size_t)tile * 4 + 0) * 64 + lane] = h0.v;
    G[((size_t)tile * 4 + 1) * 64 + lane] = h1.v;
    G[((size_t)tile * 4 + 2) * 64 + lane] = l0.v;
    G[((size_t)tile * 4 + 3) * 64 + lane] = l1.v;

    float s = e0.x * e0.x + e0.y * e0.y + e0.z * e0.z + e0.w * e0.w
            + e1.x * e1.x + e1.y * e1.y + e1.z * e1.z + e1.w * e1.w
            + e2.x * e2.x + e2.y * e2.y + e2.z * e2.z + e2.w * e2.w
            + e3.x * e3.x + e3.y * e3.y + e3.z * e3.z + e3.w * e3.w;
    s += __shfl_xor(s, 16);
    s += __shfl_xor(s, 32);
    if (lhi == 0) enorm_h[code] = 0.5f * s;
}

// ---------------- pass 1: quarter codebook per block, 32KB LDS in 2 phases ----------------
// grid: 1024 blocks = quarter q (bid>>8) x token-group t (bid&255); 512 thr
// 34 KB LDS -> 4 blocks/CU; VGPR must stay <= 64 for 8 waves/SIMD.
// unroll 2 (NOT full): full unroll hoists 32 ds_read_b128 -> VGPR blowup -> spill
// (R10/R11: FETCH 0.6-1.0 GB scratch traffic, 270-478us).
__global__ __launch_bounds__(512, 4) void vq_scan(const float* __restrict__ x,
                                                  const float* __restrict__ enorm_h,
                                                  const short8* __restrict__ G,
                                                  float2* __restrict__ pm_g,
                                                  int* __restrict__ pidx_g,
                                                  float* __restrict__ xnorm_g) {
    const int tid = threadIdx.x;
    const int lane = tid & 63;
    const int w = __builtin_amdgcn_readfirstlane(tid >> 6);  // wave 0..7
    const int lhi = lane >> 4, llo = lane & 15;
    const int q = blockIdx.x >> 8;          // codebook quarter 0..3
    const int t = blockIdx.x & 255;         // token group

    __shared__ short8 fbq[2048];            // 8 tiles x 4 frags x 64 lanes = 32 KB (one phase)
    __shared__ float en_q[256];             // 1 KB

    const int tb = t * 256;
    const int bb = tb >> 10;
    const int hwb = tb & 1023;
    const float* xbase = x + (size_t)bb * (D * HWSZ);
    const short8* Gq = G + (size_t)q * 4096;

    // ---- stage phase 0 (tiles 0..7 of the quarter) ----
#pragma unroll
    for (int j = 0; j < 4; ++j)
        __builtin_amdgcn_global_load_lds(
            (const __attribute__((address_space(1))) void*)(Gq + (size_t)j * 512 + tid),
            (__attribute__((address_space(3))) void*)&fbq[j * 512 + tid],
            16, 0, 0);
    if (tid < 256) en_q[tid] = enorm_h[q * 256 + tid];

    // ---- load & convert this wave's 32 tokens (2 sets of 16), A NEGATED ----
    // A mapping: row(token) = llo, k = lhi*8 + j, d = kh*32 + k
    short8 Ah[2][2], Al[2][2];
#pragma unroll
    for (int s = 0; s < 2; ++s) {
        const int hw = hwb + w * 32 + s * 16 + llo;
        float xn = 0.f;
        Frag ah[2], al[2];
#pragma unroll
        for (int kh = 0; kh < 2; ++kh) {
            const float* xp = xbase + (size_t)(kh * 32 + lhi * 8) * HWSZ + hw;
            float v[8];
#pragma unroll
            for (int j = 0; j < 8; ++j) { v[j] = -xp[(size_t)j * HWSZ]; xn += v[j] * v[j]; }
#pragma unroll
            for (int p = 0; p < 4; ++p)
                split2(v[2 * p], v[2 * p + 1], ah[kh].u[p], al[kh].u[p]);
        }
        xn += __shfl_xor(xn, 16);
        xn += __shfl_xor(xn, 32);
        if (q == 0 && lhi == 0) xnorm_g[tb + w * 32 + s * 16 + llo] = xn;
        Ah[s][0] = ah[0].v; Ah[s][1] = ah[1].v;
        Al[s][0] = al[0].v; Al[s][1] = al[1].v;
    }

    float m1[2][4], m2[2][4];
#pragma unroll
    for (int s = 0; s < 2; ++s)
#pragma unroll
        for (int i = 0; i < 4; ++i) { m1[s][i] = 1e30f; m2[s][i] = 1e30f; }

    __syncthreads();   // phase-0 staging complete (implicit vmcnt drain)

    // ---- hot loop: 2 phases x 8 tiles; acc seeded with 0.5||e||^2, A negated ----
    for (int h = 0; h < 2; ++h) {
        if (h) {
            __syncthreads();   // all reads of phase 0 done
#pragma unroll
            for (int j = 0; j < 4; ++j)
                __builtin_amdgcn_global_load_lds(
                    (const __attribute__((address_space(1))) void*)(Gq + 2048 + (size_t)j * 512 + tid),
                    (__attribute__((address_space(3))) void*)&fbq[j * 512 + tid],
                    16, 0, 0);
            __syncthreads();   // phase-1 staging complete
        }
#pragma unroll 2
        for (int tt = 0; tt < 8; ++tt) {
            const int tile = h * 8 + tt;
            short8 B0 = fbq[(tt * 4 + 0) * 64 + lane];   // e_hi kh0
            short8 B1 = fbq[(tt * 4 + 1) * 64 + lane];   // e_hi kh1
            short8 B2 = fbq[(tt * 4 + 2) * 64 + lane];   // e_lo kh0
            short8 B3 = fbq[(tt * 4 + 3) * 64 + lane];   // e_lo kh1
            const float en_ = en_q[tile * 16 + llo];
#pragma unroll
            for (int s = 0; s < 2; ++s) {
                floatx4 accA = {en_, en_, en_, en_};
                floatx4 accB = {0.f, 0.f, 0.f, 0.f};
                __builtin_amdgcn_s_setprio(1);
                accA = MFMA(Ah[s][0], B0, accA);
                accB = MFMA(Ah[s][1], B1, accB);
                accA = MFMA(Al[s][0], B0, accA);
                accB = MFMA(Al[s][1], B1, accB);
                accA = MFMA(Ah[s][0], B2, accA);
                accB = MFMA(Ah[s][1], B3, accB);
                __builtin_amdgcn_s_setprio(0);
#pragma unroll
                for (int i = 0; i < 4; ++i) {
                    float sc = accA[i] + accB[i];            // 0.5||e||^2 - x.e
                    unsigned pb = (__builtin_bit_cast(unsigned, sc) & 0xFFFFFFF0u) | (unsigned)tile;
                    float scp = __builtin_bit_cast(float, pb);
                    m2[s][i] = __builtin_amdgcn_fmed3f(scp, m1[s][i], m2[s][i]);
                    m1[s][i] = fminf(m1[s][i], scp);
                }
            }
        }
    }

    // ---- cross-lane argmin reduce over the 16 code-lanes; write per-quarter partials ----
#pragma unroll
    for (int s = 0; s < 2; ++s)
#pragma unroll
        for (int i = 0; i < 4; ++i) {
            float a1 = m1[s][i], a2 = m2[s][i];
            int ai = (int)(((__builtin_bit_cast(unsigned, a1) & 15u) << 4) | (unsigned)llo);
#pragma unroll
            for (int sft = 1; sft < 16; sft <<= 1) {
                float o1 = __shfl_xor(a1, sft);
                float o2 = __shfl_xor(a2, sft);
                int oi = __shfl_xor(ai, sft);
                float big = fmaxf(a1, o1);
                a2 = fminf(fminf(a2, o2), big);
                if (o1 < a1 || (o1 == a1 && oi < ai)) { a1 = o1; ai = oi; }
                ai = (int)(((__builtin_bit_cast(unsigned, a1) & 15u) << 4) | ((unsigned)ai & 15u));
            }
            if (llo == 0) {
                const int tok = tb + w * 32 + s * 16 + lhi * 4 + i;
                float m1c = __builtin_bit_cast(float, __builtin_bit_cast(unsigned, a1) & 0xFFFFFFF0u);
                float m2c = __builtin_bit_cast(float, __builtin_bit_cast(unsigned, a2) & 0xFFFFFFF0u);
                pm_g[(size_t)q * NTOK + tok] = make_float2(m1c, m2c);
                pidx_g[(size_t)q * NTOK + tok] = q * 256 + ai;
            }
        }
}

// ---------------- pass 2: merge quarters, tie rescore, loss, epilogue ----------------
__global__ __launch_bounds__(256, 4) void vq_merge(const float* __restrict__ x,
                                                   const float* __restrict__ emb,
                                                   const float2* __restrict__ pm_g,
                                                   const int* __restrict__ pidx_g,
                                                   const float* __restrict__ xnorm_g,
                                                   float* __restrict__ out,
                                                   double* __restrict__ loss_acc) {
    const int tid = threadIdx.x;
    const int lane = tid & 63;
    const int w = tid >> 6;

    __shared__ int sfinal[256];
    __shared__ double sloss[256];
    __shared__ int s_flaglist[256];
    __shared__ int s_nflag;
    __shared__ double rbv[4];
    __shared__ int rbi[4];
    __shared__ double lred[4];

    if (tid == 0) s_nflag = 0;
    __syncthreads();

    const int tb = blockIdx.x * 256;
    const int tok = tb + tid;
    const int bb = tb >> 10;
    const int hwb = tb & 1023;

    // ---- merge 4 quarter-partials ----
    float2 p0 = pm_g[tok];
    float a1 = p0.x, a2 = p0.y;
    int ai = pidx_g[tok];
#pragma unroll
    for (int qq = 1; qq < 4; ++qq) {
        float2 pq = pm_g[(size_t)qq * NTOK + tok];
        int bi = pidx_g[(size_t)qq * NTOK + tok];
        float nm2 = fminf(fmaxf(a1, pq.x), fminf(a2, pq.y));
        if (pq.x < a1 || (pq.x == a1 && bi < ai)) { a1 = pq.x; ai = bi; }
        a2 = nm2;
    }
    sfinal[tid] = ai;
    sloss[tid] = (double)(xnorm_g[tok] + 2.0f * a1);   // ||x||^2 + 2*s_min
    if (a2 - a1 < TAU_H) {
        int p = atomicAdd(&s_nflag, 1);
        s_flaglist[p] = tid;
    }
    __syncthreads();

    // ---- rare: fp64 full rescore for near-tie tokens (block-cooperative) ----
    const int nf = s_nflag;
    for (int f = 0; f < nf; ++f) {
        const int tloc = s_flaglist[f];
        const int tg = tb + tloc;
        const float* xf = x + (size_t)(tg >> 10) * (D * HWSZ) + (tg & 1023);
        double bv = 1e300;
        int bi = 0x7fffffff;
        for (int kk = tid; kk < K; kk += 256) {
            const float* ek = emb + (size_t)kk * D;
            double a = 0.0;
#pragma unroll 8
            for (int d = 0; d < D; ++d) {
                double diff = (double)xf[(size_t)d * HWSZ] - (double)ek[d];
                a += diff * diff;
            }
            if (a < bv || (a == bv && kk < bi)) { bv = a; bi = kk; }
        }
        for (int off = 32; off; off >>= 1) {
            double ov = __shfl_down(bv, off);
            int oi = __shfl_down(bi, off);
            if (ov < bv || (ov == bv && oi < bi)) { bv = ov; bi = oi; }
        }
        if (lane == 0) { rbv[w] = bv; rbi[w] = bi; }
        __syncthreads();
        if (tid == 0) {
            double fv = rbv[0];
            int fi = rbi[0];
#pragma unroll
            for (int c = 1; c < 4; ++c)
                if (rbv[c] < fv || (rbv[c] == fv && rbi[c] < fi)) { fv = rbv[c]; fi = rbi[c]; }
            sfinal[tloc] = fi;
            sloss[tloc] = fv;
        }
        __syncthreads();
    }

    // ---- loss reduce + atomic ----
    double lacc = sloss[tid];
    for (int off = 32; off; off >>= 1) lacc += __shfl_xor(lacc, off);
    if (lane == 0) lred[w] = lacc;
    __syncthreads();
    if (tid == 0) atomicAdd(loss_acc, lred[0] + lred[1] + lred[2] + lred[3]);

    // ---- epilogue: out[bb][d][hwb+tid] = emb[idx][d] (coalesced across tid per d) ----
    const int qidx = sfinal[tid];
    const floatx4* eq = (const floatx4*)(emb + (size_t)qidx * D);
    float* op = out + (size_t)bb * (D * HWSZ) + hwb + tid;
#pragma unroll
    for (int j = 0; j < 16; ++j) {
        floatx4 e4 = eq[j];
        op[(size_t)(j * 4 + 0) * HWSZ] = e4.x;
        op[(size_t)(j * 4 + 1) * HWSZ] = e4.y;
        op[(size_t)(j * 4 + 2) * HWSZ] = e4.z;
        op[(size_t)(j * 4 + 3) * HWSZ] = e4.w;
    }
}

__global__ void vq_finalize(const double* __restrict__ acc, float* __restrict__ out) {
    out[QUANT_ELEMS] = (float)(1.25 * (*acc) / (double)QUANT_ELEMS);
}

extern "C" void kernel_launch(void* const* d_in, const int* in_sizes, int n_in,
                              void* d_out, int out_size, void* d_ws, size_t ws_size,
                              hipStream_t stream) {
    const float* x = (const float*)d_in[0];
    const float* emb = (const float*)d_in[1];
    float* out = (float*)d_out;
    char* ws = (char*)d_ws;

    double* acc     = (double*)(ws);                 // 8 B
    float* enorm_h  = (float*)(ws + 4096);           // 4 KB
    short8* G       = (short8*)(ws + 16384);         // 256 KB -> ends at 278528
    float2* pm_g    = (float2*)(ws + 278528);        // 2 MB   -> ends at 2375680
    int* pidx_g     = (int*)(ws + 2375680);          // 1 MB   -> ends at 3424256
    float* xnorm_g  = (float*)(ws + 3424256);        // 256 KB -> ends at 3686400

    vq_prep<<<16, 256, 0, stream>>>(emb, acc, enorm_h, G);
    vq_scan<<<1024, 512, 0, stream>>>(x, enorm_h, G, pm_g, pidx_g, xnorm_g);
    vq_merge<<<256, 256, 0, stream>>>(x, emb, pm_g, pidx_g, xnorm_g, out, acc);
    vq_finalize<<<1, 1, 0, stream>>>(acc, out);
}